// Round 4
// baseline (679.993 us; speedup 1.0000x reference)
//
#include <hip/hip_runtime.h>
#include <hip/hip_bf16.h>

typedef __bf16 bf16x8 __attribute__((ext_vector_type(8)));
typedef __bf16 bf16x4 __attribute__((ext_vector_type(4)));
typedef __bf16 bf16x2 __attribute__((ext_vector_type(2)));
typedef float f32x4 __attribute__((ext_vector_type(4)));

#define M_MEM 32768
#define S_SEG 512
#define H_ 8
#define D_ 64
#define NKEY 33280          // M + S
#define NTILES 520          // NKEY / 64
#define LOG2E 1.44269504088896340736f
#define CMAX (14.0f * LOG2E)   // fixed softmax offset (logits ~N(0,1), max ~6.2)

// out layout (floats): y[512*8*64] | new_mem_keys | new_mem_vals | new_write_index
#define Y_OFF 0
#define NK_OFF 262144
#define WI_OFF (262144 + 2 * 16777216)

// ---------------------------------------------------------------------------
// Fused flash-attention + scatter-copy.
// Decode: h = bid&7 (-> XCD id for round-robin dispatch), qt = (bid>>3)&7,
// c = bid>>6. This co-locates the 8 q-tile blocks sharing one (c,h) K/V
// stream on ONE XCD so re-reads hit that XCD's L2 instead of HBM.
// Double-buffered LDS (one barrier per tile) + depth-2 register prefetch.
// ---------------------------------------------------------------------------
__global__ __launch_bounds__(256, 3) void fused_attn(
    const float* __restrict__ memk, const float* __restrict__ memv,
    const float* __restrict__ keys, const float* __restrict__ vals,
    const float* __restrict__ qry, const unsigned char* __restrict__ sos,
    const int* __restrict__ wip, float* __restrict__ out,
    float* __restrict__ opart, float* __restrict__ lst, int NC) {
  const int bid = blockIdx.x;
  const int tid = threadIdx.x;
  const int h = bid & 7;
  const int qt = (bid >> 3) & 7;
  const int c = bid >> 6;
  const int w = tid >> 6;
  const int lane = tid & 63;
  const int L = lane & 15;
  const int quad = lane >> 4;
  const float keep = sos[0] ? 0.0f : 1.0f;

  int wi_raw = wip[0];
  int wi = wi_raw < 0 ? 0 : (wi_raw > M_MEM - S_SEG ? M_MEM - S_SEG : wi_raw);
  if (bid == 0 && tid == 0) {
    int nwi = (int)(((long long)wi_raw + S_SEG) % M_MEM);
    if (nwi < 0) nwi += M_MEM;
    out[WI_OFF] = (float)nwi;
  }

  __shared__ __align__(16) __bf16 Ks[2][64 * 72];   // [buf][key][d]
  __shared__ __align__(16) __bf16 Vt[2][64 * 72];   // [buf][dv][key rot]
  __shared__ __align__(16) __bf16 Pt[4][16 * 64];   // per-wave P^T

  const int qrow_base = qt * 64 + w * 16;
  const int q_abs = qrow_base + L;

  // Q as B-operand fragment, scaled by log2e/8
  bf16x8 qf[2];
  {
    const float* qp = qry + ((size_t)q_abs * H_ + h) * D_;
    const float qs = 0.125f * LOG2E;
#pragma unroll
    for (int kb = 0; kb < 2; ++kb) {
      const int d = kb * 32 + quad * 8;
      float4 x0 = *(const float4*)(qp + d);
      float4 x1 = *(const float4*)(qp + d + 4);
      bf16x8 f;
      f[0] = (__bf16)(x0.x * qs); f[1] = (__bf16)(x0.y * qs);
      f[2] = (__bf16)(x0.z * qs); f[3] = (__bf16)(x0.w * qs);
      f[4] = (__bf16)(x1.x * qs); f[5] = (__bf16)(x1.y * qs);
      f[6] = (__bf16)(x1.z * qs); f[7] = (__bf16)(x1.w * qs);
      qf[kb] = f;
    }
  }

  f32x4 acc[4];  // O^T accumulator
#pragma unroll
  for (int g = 0; g < 4; ++g) acc[g] = (f32x4){0.f, 0.f, 0.f, 0.f};
  float l_acc = 0.f;

  const int tile_start = (NTILES * c) / NC;
  const int tile_end = (NTILES * (c + 1)) / NC;
  const int nt = tile_end - tile_start;

  const int kk = tid >> 2;         // K staging: key
  const int d0 = (tid & 3) * 16;   // K staging: dim base
  const int vp2 = tid & 31;        // V staging: key pair
  const int dvb = (tid >> 5) * 8;  // V staging: dv base (Vt rotation)

  float4 kreg[2][4], vreg[2][4];
  float mult[2];
  auto issue = [&](int t, int s) {
    const int tb = (tile_start + t) * 64;
    const float *kb_, *vb_;
    if (tb < M_MEM) {
      kb_ = memk + (size_t)tb * 512 + h * 64;
      vb_ = memv + (size_t)tb * 512 + h * 64;
      mult[s] = keep;
    } else {
      kb_ = keys + (size_t)(tb - M_MEM) * 512 + h * 64;
      vb_ = vals + (size_t)(tb - M_MEM) * 512 + h * 64;
      mult[s] = 1.0f;
    }
    const float* ks = kb_ + (size_t)kk * 512 + d0;
#pragma unroll
    for (int i = 0; i < 4; ++i) kreg[s][i] = *(const float4*)(ks + i * 4);
    const float* vs = vb_ + (size_t)(2 * vp2) * 512 + dvb;
    vreg[s][0] = *(const float4*)(vs);
    vreg[s][1] = *(const float4*)(vs + 4);
    vreg[s][2] = *(const float4*)(vs + 512);
    vreg[s][3] = *(const float4*)(vs + 516);
  };

  issue(0, 0);
  if (nt > 1) issue(1, 1);

  for (int t = 0; t < nt; ++t) {
    const int cur = t & 1;
    const int tb = (tile_start + t) * 64;
    const float mu = mult[cur];
    {
      // ---- K -> Ks[cur] ----
      bf16x8 lo, hi;
      lo[0] = (__bf16)(kreg[cur][0].x * mu); lo[1] = (__bf16)(kreg[cur][0].y * mu);
      lo[2] = (__bf16)(kreg[cur][0].z * mu); lo[3] = (__bf16)(kreg[cur][0].w * mu);
      lo[4] = (__bf16)(kreg[cur][1].x * mu); lo[5] = (__bf16)(kreg[cur][1].y * mu);
      lo[6] = (__bf16)(kreg[cur][1].z * mu); lo[7] = (__bf16)(kreg[cur][1].w * mu);
      hi[0] = (__bf16)(kreg[cur][2].x * mu); hi[1] = (__bf16)(kreg[cur][2].y * mu);
      hi[2] = (__bf16)(kreg[cur][2].z * mu); hi[3] = (__bf16)(kreg[cur][2].w * mu);
      hi[4] = (__bf16)(kreg[cur][3].x * mu); hi[5] = (__bf16)(kreg[cur][3].y * mu);
      hi[6] = (__bf16)(kreg[cur][3].z * mu); hi[7] = (__bf16)(kreg[cur][3].w * mu);
      *(bf16x8*)&Ks[cur][kk * 72 + d0] = lo;
      *(bf16x8*)&Ks[cur][kk * 72 + d0 + 8] = hi;
      // ---- V -> Vt[cur] transposed, key-pair packed b32 ----
      const int col = (2 * vp2 + dvb) & 63;
      float a0[8] = {vreg[cur][0].x, vreg[cur][0].y, vreg[cur][0].z, vreg[cur][0].w,
                     vreg[cur][1].x, vreg[cur][1].y, vreg[cur][1].z, vreg[cur][1].w};
      float a1[8] = {vreg[cur][2].x, vreg[cur][2].y, vreg[cur][2].z, vreg[cur][2].w,
                     vreg[cur][3].x, vreg[cur][3].y, vreg[cur][3].z, vreg[cur][3].w};
#pragma unroll
      for (int i = 0; i < 8; ++i) {
        bf16x2 pr;
        pr[0] = (__bf16)(a0[i] * mu);
        pr[1] = (__bf16)(a1[i] * mu);
        *(bf16x2*)&Vt[cur][(dvb + i) * 72 + col] = pr;
      }
      // ---- fused scatter-copy to new_mem (owning qt only) ----
      if ((((unsigned)(tb >> 6)) & 7u) == (unsigned)qt) {
        int krow = (tb < M_MEM) ? tb + kk : wi + (tb - M_MEM) + kk;
        bool kskip = (tb < M_MEM) && (krow >= wi && krow < wi + S_SEG);
        if (!kskip) {
          float* dK = out + NK_OFF + (size_t)krow * 512 + h * 64 + d0;
#pragma unroll
          for (int i = 0; i < 4; ++i) {
            float4 vv = kreg[cur][i];
            vv.x *= mu; vv.y *= mu; vv.z *= mu; vv.w *= mu;
            *(float4*)(dK + i * 4) = vv;
          }
        }
        int r0 = (tb < M_MEM) ? tb + 2 * vp2 : wi + (tb - M_MEM) + 2 * vp2;
#pragma unroll
        for (int pk2 = 0; pk2 < 2; ++pk2) {
          int vrow = r0 + pk2;
          bool vskip = (tb < M_MEM) && (vrow >= wi && vrow < wi + S_SEG);
          if (!vskip) {
            float* dV = out + NK_OFF + 16777216 + (size_t)vrow * 512 + h * 64 + dvb;
            float4 u0 = vreg[cur][pk2 * 2], u1 = vreg[cur][pk2 * 2 + 1];
            u0.x *= mu; u0.y *= mu; u0.z *= mu; u0.w *= mu;
            u1.x *= mu; u1.y *= mu; u1.z *= mu; u1.w *= mu;
            *(float4*)(dV) = u0;
            *(float4*)(dV + 4) = u1;
          }
        }
      }
    }
    __syncthreads();
    if (t + 2 < nt) issue(t + 2, cur);  // depth-2 prefetch into freed reg set

    // ---- S^T = K x Q^T ----
    f32x4 sg[4];
#pragma unroll
    for (int g = 0; g < 4; ++g) {
      bf16x8 klo = *(bf16x8*)&Ks[cur][(g * 16 + L) * 72 + quad * 8];
      bf16x8 khi = *(bf16x8*)&Ks[cur][(g * 16 + L) * 72 + 32 + quad * 8];
      f32x4 z = (f32x4){0.f, 0.f, 0.f, 0.f};
      z = __builtin_amdgcn_mfma_f32_16x16x32_bf16(klo, qf[0], z, 0, 0, 0);
      sg[g] = __builtin_amdgcn_mfma_f32_16x16x32_bf16(khi, qf[1], z, 0, 0, 0);
    }

    // ---- fixed-max softmax: p = exp2(s' - CMAX) ----
    const int prot = 8 * (L & 7);
#pragma unroll
    for (int g = 0; g < 4; ++g) {
      bf16x4 pk;
#pragma unroll
      for (int r = 0; r < 4; ++r) {
        const int kidx = tb + g * 16 + quad * 4 + r;
        float p = __builtin_amdgcn_exp2f(sg[g][r] - CMAX);
        const bool msk = (kidx >= M_MEM) && (kidx - M_MEM >= q_abs);
        p = msk ? 0.f : p;
        l_acc += p;
        pk[r] = (__bf16)p;
      }
      *(bf16x4*)&Pt[w][L * 64 + ((g * 16 + quad * 4 + prot) & 63)] = pk;
    }

    // ---- O^T += V^T x P^T ----
    bf16x8 pb0 = *(bf16x8*)&Pt[w][L * 64 + ((quad * 8 + prot) & 63)];
    bf16x8 pb1 = *(bf16x8*)&Pt[w][L * 64 + ((32 + quad * 8 + prot) & 63)];
#pragma unroll
    for (int g = 0; g < 4; ++g) {
      const int vrot = g * 16 + 8 * (L >> 3);
      bf16x8 v0 = *(bf16x8*)&Vt[cur][(g * 16 + L) * 72 + ((quad * 8 + vrot) & 63)];
      bf16x8 v1 = *(bf16x8*)&Vt[cur][(g * 16 + L) * 72 + ((32 + quad * 8 + vrot) & 63)];
      acc[g] = __builtin_amdgcn_mfma_f32_16x16x32_bf16(v0, pb0, acc[g], 0, 0, 0);
      acc[g] = __builtin_amdgcn_mfma_f32_16x16x32_bf16(v1, pb1, acc[g], 0, 0, 0);
    }
  }

  // ---- epilogue ----
  l_acc += __shfl_xor(l_acc, 16);
  l_acc += __shfl_xor(l_acc, 32);
  const size_t row = (size_t)h * S_SEG + q_abs;
#pragma unroll
  for (int g = 0; g < 4; ++g)
    *(f32x4*)&opart[(row * NC + c) * 64 + g * 16 + quad * 4] = acc[g];
  if (quad == 0) lst[row * NC + c] = l_acc;
}

// ---------------------------------------------------------------------------
__global__ __launch_bounds__(256) void combine(
    const float* __restrict__ opart, const float* __restrict__ lst,
    float* __restrict__ y, int NC) {
  const int idx = blockIdx.x * 256 + threadIdx.x;
  const int d = idx & 63;
  const int h = (idx >> 6) & 7;
  const int q = idx >> 9;
  const size_t row = (size_t)h * S_SEG + q;
  float num = 0.f, den = 0.f;
  for (int c = 0; c < NC; ++c) {
    num += opart[(row * NC + c) * 64 + d];
    den += lst[row * NC + c];
  }
  y[idx] = num / den;
}

// ---------------------------------------------------------------------------
extern "C" void kernel_launch(void* const* d_in, const int* in_sizes, int n_in,
                              void* d_out, int out_size, void* d_ws, size_t ws_size,
                              hipStream_t stream) {
  const float* memk = (const float*)d_in[0];
  const float* memv = (const float*)d_in[1];
  const float* keys = (const float*)d_in[2];
  const float* vals = (const float*)d_in[3];
  const float* qry  = (const float*)d_in[4];
  const unsigned char* sos = (const unsigned char*)d_in[5];
  const int* wip = (const int*)d_in[6];
  float* out = (float*)d_out;

  // NC=12 -> grid 768 = 3 blocks/CU in one resident round (LDS-limited at 45KB)
  static const int cand[] = {12, 8, 4, 2, 1};
  int NC = 1;
  for (int i = 0; i < 5; ++i) {
    size_t need = (size_t)cand[i] *
        ((size_t)H_ * S_SEG * D_ * 4 + (size_t)H_ * S_SEG * 4);
    if (need <= ws_size) { NC = cand[i]; break; }
  }

  float* opart = (float*)d_ws;
  float* lstp = opart + (size_t)H_ * S_SEG * NC * D_;

  fused_attn<<<NC * 64, 256, 0, stream>>>(
      memk, memv, keys, vals, qry, sos, wip, out, opart, lstp, NC);

  combine<<<1024, 256, 0, stream>>>(opart, lstp, out + Y_OFF, NC);
}